// Round 1
// baseline (509.789 us; speedup 1.0000x reference)
//
#include <hip/hip_runtime.h>
#include <hip/hip_bf16.h>
#include <math.h>

using bf16 = __hip_bfloat16;
typedef short bf16x8 __attribute__((ext_vector_type(8)));
typedef float f32x4 __attribute__((ext_vector_type(4)));

#define GAMMA_LOG2 (-0.0014434688536725045f)  // log2(0.999)

// ---------- transpose + cast: fp32 (R x C) -> bf16 (C x R); R,C multiples of 32 ----------
__global__ void k_transpose_cast(const float* __restrict__ in, bf16* __restrict__ out, int R, int C)
{
    __shared__ float tile[32][33];
    int c0 = blockIdx.x * 32, r0 = blockIdx.y * 32;
    int tx = threadIdx.x & 31, ty = threadIdx.x >> 5;  // 256 threads: ty in 0..7
#pragma unroll
    for (int i = 0; i < 4; ++i) {
        int r = r0 + ty + 8 * i;
        tile[ty + 8 * i][tx] = in[(size_t)r * C + c0 + tx];
    }
    __syncthreads();
#pragma unroll
    for (int i = 0; i < 4; ++i) {
        int cc = c0 + ty + 8 * i, rr = r0 + tx;
        out[(size_t)cc * R + rr] = __float2bfloat16(tile[tx][ty + 8 * i]);
    }
}

// ---------- block reduction over 512 elems held 2-per-thread by 256 threads ----------
__device__ inline float block_sum_512(float v)
{
#pragma unroll
    for (int m = 32; m >= 1; m >>= 1) v += __shfl_xor(v, m, 64);
    __shared__ float ws[4];
    if ((threadIdx.x & 63) == 0) ws[threadIdx.x >> 6] = v;
    __syncthreads();
    return ws[0] + ws[1] + ws[2] + ws[3];
}

// ---------- x -> srms(x) as bf16 (rows of 512) ----------
__global__ void k_rms_x(const float* __restrict__ x, bf16* __restrict__ xn)
{
    int row = blockIdx.x, t = threadIdx.x;
    const float* xr = x + (size_t)row * 512;
    float a = xr[t], b = xr[t + 256];
    float tot = block_sum_512(a * a + b * b);
    float s = 1.f / (sqrtf(tot * (1.f / 512.f)) + 1e-8f);
    bf16* o = xn + (size_t)row * 512;
    o[t] = __float2bfloat16(a * s);
    o[t + 256] = __float2bfloat16(b * s);
}

// ---------- hcf0 = n*Wp + bp ; out = relu(srms(hcf0)) bf16 ----------
__global__ void k_mlp0(const float* __restrict__ Wp, const float* __restrict__ bp, bf16* __restrict__ out)
{
    int n = blockIdx.x, t = threadIdx.x;
    float fn = (float)n;
    float a = fn * Wp[t] + bp[t];
    float b = fn * Wp[t + 256] + bp[t + 256];
    float tot = block_sum_512(a * a + b * b);
    float s = 1.f / (sqrtf(tot * (1.f / 512.f)) + 1e-8f);
    bf16* o = out + (size_t)n * 512;
    o[t] = __float2bfloat16(fmaxf(a * s, 0.f));
    o[t + 256] = __float2bfloat16(fmaxf(b * s, 0.f));
}

// ---------- fp32 (rows x 512) -> relu(srms(.)) bf16 ----------
__global__ void k_srms_relu(const float* __restrict__ in, bf16* __restrict__ out)
{
    int row = blockIdx.x, t = threadIdx.x;
    const float* xr = in + (size_t)row * 512;
    float a = xr[t], b = xr[t + 256];
    float tot = block_sum_512(a * a + b * b);
    float s = 1.f / (sqrtf(tot * (1.f / 512.f)) + 1e-8f);
    bf16* o = out + (size_t)row * 512;
    o[t] = __float2bfloat16(fmaxf(a * s, 0.f));
    o[t + 256] = __float2bfloat16(fmaxf(b * s, 0.f));
}

// ---------- MFMA bf16 GEMM: A (MxK) row-major, Bt (NxK) row-major (pre-transposed weights) ----------
enum { EPI_SILU_BF16 = 0, EPI_BIAS_F32 = 1, EPI_DECAY_BF16 = 2, EPI_BIAS_ADD_F32 = 3 };

template <int BM, int BN, int WM, int WN, int EPI>
__global__ __launch_bounds__(256, 2) void k_gemm(
    const bf16* __restrict__ A, const bf16* __restrict__ Bt,
    const float* __restrict__ bias0, const float* __restrict__ bias1, int bsplit,
    const float* __restrict__ addsrc, void* __restrict__ outp,
    int M, int N, int K)
{
    constexpr int BK = 32, LDT = BK + 8;  // +8 bf16 pad -> 80B row stride, conflict-benign, 16B aligned
    constexpr int MI = WM / 16, NJ = WN / 16;
    constexpr int WCOLS = BN / WN;
    __shared__ unsigned short As[BM * LDT];
    __shared__ unsigned short Bs[BN * LDT];
    const int tid = threadIdx.x;
    const int lane = tid & 63, w = tid >> 6;
    const int wm = (w / WCOLS) * WM, wn = (w % WCOLS) * WN;
    const int lm = lane & 15, lq = lane >> 4;
    const long rowBase = (long)blockIdx.x * BM, colBase = (long)blockIdx.y * BN;

    f32x4 acc[MI][NJ];
    f32x4 zz = {0.f, 0.f, 0.f, 0.f};
#pragma unroll
    for (int i = 0; i < MI; ++i)
#pragma unroll
        for (int j = 0; j < NJ; ++j) acc[i][j] = zz;

    for (int k0 = 0; k0 < K; k0 += BK) {
#pragma unroll
        for (int i = 0; i < BM / 64; ++i) {
            int idx = (i * 256 + tid) * 8;
            int r = idx >> 5, kk = idx & 31;
            *(uint4*)(void*)(As + r * LDT + kk) =
                *(const uint4*)(const void*)(A + (rowBase + r) * K + k0 + kk);
        }
#pragma unroll
        for (int i = 0; i < BN / 64; ++i) {
            int idx = (i * 256 + tid) * 8;
            int r = idx >> 5, kk = idx & 31;
            *(uint4*)(void*)(Bs + r * LDT + kk) =
                *(const uint4*)(const void*)(Bt + (colBase + r) * K + k0 + kk);
        }
        __syncthreads();
        bf16x8 af[MI], bfr[NJ];
#pragma unroll
        for (int mi = 0; mi < MI; ++mi)
            af[mi] = *(const bf16x8*)(const void*)(As + (wm + mi * 16 + lm) * LDT + lq * 8);
#pragma unroll
        for (int nj = 0; nj < NJ; ++nj)
            bfr[nj] = *(const bf16x8*)(const void*)(Bs + (wn + nj * 16 + lm) * LDT + lq * 8);
#pragma unroll
        for (int mi = 0; mi < MI; ++mi)
#pragma unroll
            for (int nj = 0; nj < NJ; ++nj)
                acc[mi][nj] = __builtin_amdgcn_mfma_f32_16x16x32_bf16(af[mi], bfr[nj], acc[mi][nj], 0, 0, 0);
        __syncthreads();
    }

    // C/D layout (m89-verified): col = lane&15, row = (lane>>4)*4 + reg
#pragma unroll
    for (int mi = 0; mi < MI; ++mi)
#pragma unroll
        for (int nj = 0; nj < NJ; ++nj) {
            long col = colBase + wn + nj * 16 + lm;
#pragma unroll
            for (int r = 0; r < 4; ++r) {
                long row = rowBase + wm + mi * 16 + lq * 4 + r;
                float z = acc[mi][nj][r];
                size_t off = (size_t)row * N + col;
                if constexpr (EPI == EPI_SILU_BF16) {
                    float bb = (col < bsplit) ? bias0[col] : bias1[col - bsplit];
                    z += bb;
                    z = z / (1.f + __expf(-z));
                    ((bf16*)outp)[off] = __float2bfloat16(z);
                } else if constexpr (EPI == EPI_BIAS_F32) {
                    ((float*)outp)[off] = z + bias0[col];
                } else if constexpr (EPI == EPI_DECAY_BF16) {
                    z += bias0[col];
                    z *= exp2f((float)row * GAMMA_LOG2);  // gamma^row, row 0 -> 1
                    ((bf16*)outp)[off] = __float2bfloat16(z);
                } else {  // EPI_BIAS_ADD_F32: + bias + residual x
                    ((float*)outp)[off] = z + bias0[col] + addsrc[off];
                }
            }
        }
}

// ---------- depthwise causal conv + gate: ud1[b,t,c] = u[b,t,c] * sum_{s<=t} v[b,s,c]*a[t-s,c] ----------
// uv: (8192 x 2048) bf16 (cols 0..1023 = u, 1024..2047 = v); abuf: (2048 x 1024) bf16
// block: 256 thr = 64 channels x 4 batches; tile: 32 t-outputs; s chunked by 16 with 47-tap reg window
__global__ __launch_bounds__(256, 2) void k_conv(
    const bf16* __restrict__ uv, const bf16* __restrict__ abuf, bf16* __restrict__ ud1)
{
    const int t0 = (63 - (int)blockIdx.y) * 32;  // heavy tiles dispatch first
    const int c = blockIdx.x * 64 + (threadIdx.x & 63);
    const int b = threadIdx.x >> 6;
    const bf16* vp = uv + (size_t)b * 2048 * 2048 + 1024 + c;
    const bf16* ap = abuf + c;
    float acc[32];
#pragma unroll
    for (int i = 0; i < 32; ++i) acc[i] = 0.f;

    for (int s0 = 0; s0 < t0; s0 += 16) {
        float W[47], V[16];
        const int kb = t0 - s0 - 15;
#pragma unroll
        for (int j = 0; j < 47; ++j) W[j] = __bfloat162float(ap[(size_t)(kb + j) * 1024]);
#pragma unroll
        for (int ss = 0; ss < 16; ++ss) V[ss] = __bfloat162float(vp[(size_t)(s0 + ss) * 2048]);
#pragma unroll
        for (int ss = 0; ss < 16; ++ss)
#pragma unroll
            for (int t = 0; t < 32; ++t)
                acc[t] += V[ss] * W[15 + t - ss];  // a[(t0+t)-(s0+ss)]
    }
    {   // diagonal block s in [t0, t0+32), causal-masked at compile time
        float W[32], V[32];
#pragma unroll
        for (int j = 0; j < 32; ++j) W[j] = __bfloat162float(ap[(size_t)j * 1024]);
#pragma unroll
        for (int ss = 0; ss < 32; ++ss) V[ss] = __bfloat162float(vp[(size_t)(t0 + ss) * 2048]);
#pragma unroll
        for (int ss = 0; ss < 32; ++ss)
#pragma unroll
            for (int t = ss; t < 32; ++t)
                acc[t] += V[ss] * W[t - ss];
    }
    const bf16* up = uv + (size_t)b * 2048 * 2048 + c;
    bf16* op = ud1 + (size_t)b * 2048 * 1024 + c;
#pragma unroll
    for (int t = 0; t < 32; ++t) {
        float u = __bfloat162float(up[(size_t)(t0 + t) * 2048]);
        op[(size_t)(t0 + t) * 1024] = __float2bfloat16(u * acc[t]);
    }
}

extern "C" void kernel_launch(void* const* d_in, const int* in_sizes, int n_in,
                              void* d_out, int out_size, void* d_ws, size_t ws_size,
                              hipStream_t stream)
{
    const float* x  = (const float*)d_in[0];
    const float* Wu = (const float*)d_in[1];
    const float* bu = (const float*)d_in[2];
    const float* Wv = (const float*)d_in[3];
    const float* bv = (const float*)d_in[4];
    const float* Wo = (const float*)d_in[5];
    const float* bo = (const float*)d_in[6];
    const float* Wp = (const float*)d_in[7];
    const float* bp = (const float*)d_in[8];
    const float* W1 = (const float*)d_in[9];
    const float* b1 = (const float*)d_in[10];
    const float* W2 = (const float*)d_in[11];
    const float* b2 = (const float*)d_in[12];
    const float* W3 = (const float*)d_in[13];
    const float* b3 = (const float*)d_in[14];
    const float* Wz = (const float*)d_in[15];
    const float* bz = (const float*)d_in[16];

    char* p = (char*)d_ws;
    auto carve = [&](size_t bytes) { void* q = (void*)p; p += (bytes + 255) & ~(size_t)255; return q; };
    bf16*  xn   = (bf16*)carve((size_t)8192 * 512 * 2);
    bf16*  Wuvt = (bf16*)carve((size_t)2048 * 512 * 2);   // [Wu^T ; Wv^T], (2048 x 512)
    bf16*  Wot  = (bf16*)carve((size_t)512 * 1024 * 2);   // Wo^T (512 x 1024)
    bf16*  W1t  = (bf16*)carve((size_t)512 * 512 * 2);
    bf16*  W2t  = (bf16*)carve((size_t)512 * 512 * 2);
    bf16*  W3t  = (bf16*)carve((size_t)512 * 512 * 2);
    bf16*  Wzt  = (bf16*)carve((size_t)1024 * 512 * 2);   // Wz^T (1024 x 512)
    bf16*  uvb  = (bf16*)carve((size_t)8192 * 2048 * 2);  // [u | v] silu outputs
    bf16*  ud1  = (bf16*)carve((size_t)8192 * 1024 * 2);  // u * conv
    bf16*  hb   = (bf16*)carve((size_t)2048 * 512 * 2);   // relu(srms(.)) bf16
    float* hf   = (float*)carve((size_t)2048 * 512 * 4);  // raw MLP GEMM out
    bf16*  ab   = (bf16*)carve((size_t)2048 * 1024 * 2);  // decayed filter a[k,c]

    // weight prep (transpose+cast so GEMM B-operand is k-contiguous)
    k_transpose_cast<<<dim3(32, 16), 256, 0, stream>>>(Wu, Wuvt, 512, 1024);
    k_transpose_cast<<<dim3(32, 16), 256, 0, stream>>>(Wv, Wuvt + (size_t)1024 * 512, 512, 1024);
    k_transpose_cast<<<dim3(16, 32), 256, 0, stream>>>(Wo, Wot, 1024, 512);
    k_transpose_cast<<<dim3(16, 16), 256, 0, stream>>>(W1, W1t, 512, 512);
    k_transpose_cast<<<dim3(16, 16), 256, 0, stream>>>(W2, W2t, 512, 512);
    k_transpose_cast<<<dim3(16, 16), 256, 0, stream>>>(W3, W3t, 512, 512);
    k_transpose_cast<<<dim3(32, 16), 256, 0, stream>>>(Wz, Wzt, 512, 1024);

    k_rms_x<<<8192, 256, 0, stream>>>(x, xn);

    // u|v = silu(xn @ [Wu|Wv] + [bu|bv])
    k_gemm<128, 128, 64, 64, EPI_SILU_BF16><<<dim3(64, 16), 256, 0, stream>>>(
        xn, Wuvt, bu, bv, 1024, nullptr, uvb, 8192, 2048, 512);

    // positional filter MLP
    k_mlp0<<<2048, 256, 0, stream>>>(Wp, bp, hb);
    k_gemm<64, 64, 32, 32, EPI_BIAS_F32><<<dim3(32, 8), 256, 0, stream>>>(
        hb, W1t, b1, nullptr, 0, nullptr, hf, 2048, 512, 512);
    k_srms_relu<<<2048, 256, 0, stream>>>(hf, hb);
    k_gemm<64, 64, 32, 32, EPI_BIAS_F32><<<dim3(32, 8), 256, 0, stream>>>(
        hb, W2t, b2, nullptr, 0, nullptr, hf, 2048, 512, 512);
    k_srms_relu<<<2048, 256, 0, stream>>>(hf, hb);
    k_gemm<64, 64, 32, 32, EPI_BIAS_F32><<<dim3(32, 8), 256, 0, stream>>>(
        hb, W3t, b3, nullptr, 0, nullptr, hf, 2048, 512, 512);
    k_srms_relu<<<2048, 256, 0, stream>>>(hf, hb);
    // a[k,c] = gamma^k * (hb @ Wz + bz)[k,c]
    k_gemm<64, 64, 32, 32, EPI_DECAY_BF16><<<dim3(32, 16), 256, 0, stream>>>(
        hb, Wzt, bz, nullptr, 0, nullptr, ab, 2048, 1024, 512);

    // causal depthwise long conv + gate by u
    k_conv<<<dim3(16, 64), 256, 0, stream>>>(uvb, ab, ud1);

    // y = ud1 @ Wo + bo + x
    k_gemm<128, 128, 64, 64, EPI_BIAS_ADD_F32><<<dim3(64, 4), 256, 0, stream>>>(
        ud1, Wot, bo, nullptr, 0, x, d_out, 8192, 512, 1024);
}

// Round 2
// 487.292 us; speedup vs baseline: 1.0462x; 1.0462x over previous
//
#include <hip/hip_runtime.h>
#include <hip/hip_bf16.h>
#include <math.h>

using bf16 = __hip_bfloat16;
typedef short bf16x8 __attribute__((ext_vector_type(8)));
typedef float f32x4 __attribute__((ext_vector_type(4)));
typedef float f32x2 __attribute__((ext_vector_type(2)));

#define GAMMA_LOG2 (-0.0014434688536725045f)  // log2(0.999)

// packed 2xf32 FMA: d = a*b + c (one VOP3P inst, 2 MACs/lane)
__device__ inline f32x2 pk_fma(f32x2 a, f32x2 b, f32x2 c)
{
    f32x2 d;
    asm("v_pk_fma_f32 %0, %1, %2, %3" : "=v"(d) : "v"(a), "v"(b), "v"(c));
    return d;
}

// 2 packed bf16 (in a dword) -> f32x2; 1 VALU op per value (shift / mask)
__device__ inline f32x2 bf2f(unsigned int u)
{
    f32x2 r;
    r.x = __uint_as_float(u << 16);
    r.y = __uint_as_float(u & 0xffff0000u);
    return r;
}

__device__ inline unsigned int packbf2(float a, float b)
{
    union { bf16 h; unsigned short s; } x, y;
    x.h = __float2bfloat16(a);
    y.h = __float2bfloat16(b);
    return (unsigned int)x.s | ((unsigned int)y.s << 16);
}

// ---------- transpose + cast: fp32 (R x C) -> bf16 (C x R); R,C multiples of 32 ----------
__global__ void k_transpose_cast(const float* __restrict__ in, bf16* __restrict__ out, int R, int C)
{
    __shared__ float tile[32][33];
    int c0 = blockIdx.x * 32, r0 = blockIdx.y * 32;
    int tx = threadIdx.x & 31, ty = threadIdx.x >> 5;  // 256 threads: ty in 0..7
#pragma unroll
    for (int i = 0; i < 4; ++i) {
        int r = r0 + ty + 8 * i;
        tile[ty + 8 * i][tx] = in[(size_t)r * C + c0 + tx];
    }
    __syncthreads();
#pragma unroll
    for (int i = 0; i < 4; ++i) {
        int cc = c0 + ty + 8 * i, rr = r0 + tx;
        out[(size_t)cc * R + rr] = __float2bfloat16(tile[tx][ty + 8 * i]);
    }
}

// ---------- block reduction over 512 elems held 2-per-thread by 256 threads ----------
__device__ inline float block_sum_512(float v)
{
#pragma unroll
    for (int m = 32; m >= 1; m >>= 1) v += __shfl_xor(v, m, 64);
    __shared__ float ws[4];
    if ((threadIdx.x & 63) == 0) ws[threadIdx.x >> 6] = v;
    __syncthreads();
    return ws[0] + ws[1] + ws[2] + ws[3];
}

// ---------- x -> srms(x) as bf16 (rows of 512) ----------
__global__ void k_rms_x(const float* __restrict__ x, bf16* __restrict__ xn)
{
    int row = blockIdx.x, t = threadIdx.x;
    const float* xr = x + (size_t)row * 512;
    float a = xr[t], b = xr[t + 256];
    float tot = block_sum_512(a * a + b * b);
    float s = 1.f / (sqrtf(tot * (1.f / 512.f)) + 1e-8f);
    bf16* o = xn + (size_t)row * 512;
    o[t] = __float2bfloat16(a * s);
    o[t + 256] = __float2bfloat16(b * s);
}

// ---------- hcf0 = n*Wp + bp ; out = relu(srms(hcf0)) bf16 ----------
__global__ void k_mlp0(const float* __restrict__ Wp, const float* __restrict__ bp, bf16* __restrict__ out)
{
    int n = blockIdx.x, t = threadIdx.x;
    float fn = (float)n;
    float a = fn * Wp[t] + bp[t];
    float b = fn * Wp[t + 256] + bp[t + 256];
    float tot = block_sum_512(a * a + b * b);
    float s = 1.f / (sqrtf(tot * (1.f / 512.f)) + 1e-8f);
    bf16* o = out + (size_t)n * 512;
    o[t] = __float2bfloat16(fmaxf(a * s, 0.f));
    o[t + 256] = __float2bfloat16(fmaxf(b * s, 0.f));
}

// ---------- fp32 (rows x 512) -> relu(srms(.)) bf16 ----------
__global__ void k_srms_relu(const float* __restrict__ in, bf16* __restrict__ out)
{
    int row = blockIdx.x, t = threadIdx.x;
    const float* xr = in + (size_t)row * 512;
    float a = xr[t], b = xr[t + 256];
    float tot = block_sum_512(a * a + b * b);
    float s = 1.f / (sqrtf(tot * (1.f / 512.f)) + 1e-8f);
    bf16* o = out + (size_t)row * 512;
    o[t] = __float2bfloat16(fmaxf(a * s, 0.f));
    o[t + 256] = __float2bfloat16(fmaxf(b * s, 0.f));
}

// ---------- MFMA bf16 GEMM: A (MxK) row-major, Bt (NxK) row-major (pre-transposed weights) ----------
enum { EPI_SILU_BF16 = 0, EPI_BIAS_F32 = 1, EPI_DECAY_BF16 = 2, EPI_BIAS_ADD_F32 = 3 };

template <int BM, int BN, int WM, int WN, int EPI>
__global__ __launch_bounds__(256, 2) void k_gemm(
    const bf16* __restrict__ A, const bf16* __restrict__ Bt,
    const float* __restrict__ bias0, const float* __restrict__ bias1, int bsplit,
    const float* __restrict__ addsrc, void* __restrict__ outp,
    int M, int N, int K)
{
    constexpr int BK = 32, LDT = BK + 8;  // +8 bf16 pad -> 80B row stride, conflict-benign, 16B aligned
    constexpr int MI = WM / 16, NJ = WN / 16;
    constexpr int WCOLS = BN / WN;
    __shared__ unsigned short As[BM * LDT];
    __shared__ unsigned short Bs[BN * LDT];
    const int tid = threadIdx.x;
    const int lane = tid & 63, w = tid >> 6;
    const int wm = (w / WCOLS) * WM, wn = (w % WCOLS) * WN;
    const int lm = lane & 15, lq = lane >> 4;
    const long rowBase = (long)blockIdx.x * BM, colBase = (long)blockIdx.y * BN;

    f32x4 acc[MI][NJ];
    f32x4 zz = {0.f, 0.f, 0.f, 0.f};
#pragma unroll
    for (int i = 0; i < MI; ++i)
#pragma unroll
        for (int j = 0; j < NJ; ++j) acc[i][j] = zz;

    for (int k0 = 0; k0 < K; k0 += BK) {
#pragma unroll
        for (int i = 0; i < BM / 64; ++i) {
            int idx = (i * 256 + tid) * 8;
            int r = idx >> 5, kk = idx & 31;
            *(uint4*)(void*)(As + r * LDT + kk) =
                *(const uint4*)(const void*)(A + (rowBase + r) * K + k0 + kk);
        }
#pragma unroll
        for (int i = 0; i < BN / 64; ++i) {
            int idx = (i * 256 + tid) * 8;
            int r = idx >> 5, kk = idx & 31;
            *(uint4*)(void*)(Bs + r * LDT + kk) =
                *(const uint4*)(const void*)(Bt + (colBase + r) * K + k0 + kk);
        }
        __syncthreads();
        bf16x8 af[MI], bfr[NJ];
#pragma unroll
        for (int mi = 0; mi < MI; ++mi)
            af[mi] = *(const bf16x8*)(const void*)(As + (wm + mi * 16 + lm) * LDT + lq * 8);
#pragma unroll
        for (int nj = 0; nj < NJ; ++nj)
            bfr[nj] = *(const bf16x8*)(const void*)(Bs + (wn + nj * 16 + lm) * LDT + lq * 8);
#pragma unroll
        for (int mi = 0; mi < MI; ++mi)
#pragma unroll
            for (int nj = 0; nj < NJ; ++nj)
                acc[mi][nj] = __builtin_amdgcn_mfma_f32_16x16x32_bf16(af[mi], bfr[nj], acc[mi][nj], 0, 0, 0);
        __syncthreads();
    }

    // C/D layout (m89-verified): col = lane&15, row = (lane>>4)*4 + reg
#pragma unroll
    for (int mi = 0; mi < MI; ++mi)
#pragma unroll
        for (int nj = 0; nj < NJ; ++nj) {
            long col = colBase + wn + nj * 16 + lm;
#pragma unroll
            for (int r = 0; r < 4; ++r) {
                long row = rowBase + wm + mi * 16 + lq * 4 + r;
                float z = acc[mi][nj][r];
                size_t off = (size_t)row * N + col;
                if constexpr (EPI == EPI_SILU_BF16) {
                    float bb = (col < bsplit) ? bias0[col] : bias1[col - bsplit];
                    z += bb;
                    z = z / (1.f + __expf(-z));
                    ((bf16*)outp)[off] = __float2bfloat16(z);
                } else if constexpr (EPI == EPI_BIAS_F32) {
                    ((float*)outp)[off] = z + bias0[col];
                } else if constexpr (EPI == EPI_DECAY_BF16) {
                    z += bias0[col];
                    z *= exp2f((float)row * GAMMA_LOG2);  // gamma^row, row 0 -> 1
                    ((bf16*)outp)[off] = __float2bfloat16(z);
                } else {  // EPI_BIAS_ADD_F32: + bias + residual x
                    ((float*)outp)[off] = z + bias0[col] + addsrc[off];
                }
            }
        }
}

// ---------- depthwise causal conv + gate ----------
// ud1[b,t,c] = u[b,t,c] * sum_{s<=t} v[b,s,c]*a[t-s,c]
// uv: (8192 x 2048) bf16 (cols 0..1023 = u, 1024..2047 = v); abuf: (2048 x 1024) bf16
// One wave per block; each thread owns a CHANNEL PAIR (f32x2 + v_pk_fma_f32).
// Tile: 16 t-outputs; s chunked by 32 with a 47-tap register W window shared by
// two 16-s V halves. blockIdx.x = (cg | b<<3) fast-varying; y = t-tile, heavy first.
__global__ __launch_bounds__(64, 2) void k_conv(
    const bf16* __restrict__ uv, const bf16* __restrict__ abuf, bf16* __restrict__ ud1)
{
    const int t0 = (127 - (int)blockIdx.y) * 16;  // heavy tiles dispatch first
    const int cg = blockIdx.x & 7, b = blockIdx.x >> 3;
    const int c = cg * 128 + (int)threadIdx.x * 2;
    const unsigned int* vp = (const unsigned int*)(uv + (size_t)b * 2048 * 2048 + 1024 + c);
    const unsigned int* ap = (const unsigned int*)(abuf + c);
    // strides in dwords: uv row = 1024, abuf row = 512

    f32x2 acc[16];
#pragma unroll
    for (int i = 0; i < 16; ++i) acc[i] = (f32x2){0.f, 0.f};

    const int full32 = t0 >> 5;
    for (int i = 0; i < full32; ++i) {
        const int s0 = i * 32;
        const int kb = t0 - s0 - 31;  // >= 1
        f32x2 W[47];
#pragma unroll
        for (int j = 0; j < 47; ++j) W[j] = bf2f(ap[(size_t)(kb + j) * 512]);
        f32x2 V[16];
#pragma unroll
        for (int ss = 0; ss < 16; ++ss) V[ss] = bf2f(vp[(size_t)(s0 + ss) * 1024]);
#pragma unroll
        for (int ss = 0; ss < 16; ++ss)
#pragma unroll
            for (int t = 0; t < 16; ++t)
                acc[t] = pk_fma(V[ss], W[t - ss + 31], acc[t]);  // k = t0+t-(s0+ss)
#pragma unroll
        for (int ss = 0; ss < 16; ++ss) V[ss] = bf2f(vp[(size_t)(s0 + 16 + ss) * 1024]);
#pragma unroll
        for (int ss = 0; ss < 16; ++ss)
#pragma unroll
            for (int t = 0; t < 16; ++t)
                acc[t] = pk_fma(V[ss], W[t - ss + 15], acc[t]);  // k = t0+t-(s0+16+ss)
    }
    if (t0 & 16) {  // one extra 16-s chunk: s in [t0-16, t0), k = 16+t-ss in [1,31]
        const int s0 = t0 - 16;
        f32x2 W[31], V[16];
#pragma unroll
        for (int j = 0; j < 31; ++j) W[j] = bf2f(ap[(size_t)(1 + j) * 512]);
#pragma unroll
        for (int ss = 0; ss < 16; ++ss) V[ss] = bf2f(vp[(size_t)(s0 + ss) * 1024]);
#pragma unroll
        for (int ss = 0; ss < 16; ++ss)
#pragma unroll
            for (int t = 0; t < 16; ++t)
                acc[t] = pk_fma(V[ss], W[15 + t - ss], acc[t]);
    }
    {   // diagonal block: s in [t0, t0+16), causal-masked at compile time
        f32x2 W[16], V[16];
#pragma unroll
        for (int j = 0; j < 16; ++j) W[j] = bf2f(ap[(size_t)j * 512]);
#pragma unroll
        for (int ss = 0; ss < 16; ++ss) V[ss] = bf2f(vp[(size_t)(t0 + ss) * 1024]);
#pragma unroll
        for (int ss = 0; ss < 16; ++ss)
#pragma unroll
            for (int t = ss; t < 16; ++t)
                acc[t] = pk_fma(V[ss], W[t - ss], acc[t]);
    }
    // gate by u and store packed bf16 pair
    const unsigned int* up = (const unsigned int*)(uv + (size_t)b * 2048 * 2048 + c);
    unsigned int* op = (unsigned int*)(ud1 + (size_t)b * 2048 * 1024 + c);
#pragma unroll
    for (int t = 0; t < 16; ++t) {
        f32x2 u = bf2f(up[(size_t)(t0 + t) * 1024]);
        op[(size_t)(t0 + t) * 512] = packbf2(u.x * acc[t].x, u.y * acc[t].y);
    }
}

extern "C" void kernel_launch(void* const* d_in, const int* in_sizes, int n_in,
                              void* d_out, int out_size, void* d_ws, size_t ws_size,
                              hipStream_t stream)
{
    const float* x  = (const float*)d_in[0];
    const float* Wu = (const float*)d_in[1];
    const float* bu = (const float*)d_in[2];
    const float* Wv = (const float*)d_in[3];
    const float* bv = (const float*)d_in[4];
    const float* Wo = (const float*)d_in[5];
    const float* bo = (const float*)d_in[6];
    const float* Wp = (const float*)d_in[7];
    const float* bp = (const float*)d_in[8];
    const float* W1 = (const float*)d_in[9];
    const float* b1 = (const float*)d_in[10];
    const float* W2 = (const float*)d_in[11];
    const float* b2 = (const float*)d_in[12];
    const float* W3 = (const float*)d_in[13];
    const float* b3 = (const float*)d_in[14];
    const float* Wz = (const float*)d_in[15];
    const float* bz = (const float*)d_in[16];

    char* p = (char*)d_ws;
    auto carve = [&](size_t bytes) { void* q = (void*)p; p += (bytes + 255) & ~(size_t)255; return q; };
    bf16*  xn   = (bf16*)carve((size_t)8192 * 512 * 2);
    bf16*  Wuvt = (bf16*)carve((size_t)2048 * 512 * 2);   // [Wu^T ; Wv^T], (2048 x 512)
    bf16*  Wot  = (bf16*)carve((size_t)512 * 1024 * 2);   // Wo^T (512 x 1024)
    bf16*  W1t  = (bf16*)carve((size_t)512 * 512 * 2);
    bf16*  W2t  = (bf16*)carve((size_t)512 * 512 * 2);
    bf16*  W3t  = (bf16*)carve((size_t)512 * 512 * 2);
    bf16*  Wzt  = (bf16*)carve((size_t)1024 * 512 * 2);   // Wz^T (1024 x 512)
    bf16*  uvb  = (bf16*)carve((size_t)8192 * 2048 * 2);  // [u | v] silu outputs
    bf16*  ud1  = (bf16*)carve((size_t)8192 * 1024 * 2);  // u * conv
    bf16*  hb   = (bf16*)carve((size_t)2048 * 512 * 2);   // relu(srms(.)) bf16
    float* hf   = (float*)carve((size_t)2048 * 512 * 4);  // raw MLP GEMM out
    bf16*  ab   = (bf16*)carve((size_t)2048 * 1024 * 2);  // decayed filter a[k,c]

    // weight prep (transpose+cast so GEMM B-operand is k-contiguous)
    k_transpose_cast<<<dim3(32, 16), 256, 0, stream>>>(Wu, Wuvt, 512, 1024);
    k_transpose_cast<<<dim3(32, 16), 256, 0, stream>>>(Wv, Wuvt + (size_t)1024 * 512, 512, 1024);
    k_transpose_cast<<<dim3(16, 32), 256, 0, stream>>>(Wo, Wot, 1024, 512);
    k_transpose_cast<<<dim3(16, 16), 256, 0, stream>>>(W1, W1t, 512, 512);
    k_transpose_cast<<<dim3(16, 16), 256, 0, stream>>>(W2, W2t, 512, 512);
    k_transpose_cast<<<dim3(16, 16), 256, 0, stream>>>(W3, W3t, 512, 512);
    k_transpose_cast<<<dim3(32, 16), 256, 0, stream>>>(Wz, Wzt, 512, 1024);

    k_rms_x<<<8192, 256, 0, stream>>>(x, xn);

    // u|v = silu(xn @ [Wu|Wv] + [bu|bv])
    k_gemm<128, 128, 64, 64, EPI_SILU_BF16><<<dim3(64, 16), 256, 0, stream>>>(
        xn, Wuvt, bu, bv, 1024, nullptr, uvb, 8192, 2048, 512);

    // positional filter MLP
    k_mlp0<<<2048, 256, 0, stream>>>(Wp, bp, hb);
    k_gemm<64, 64, 32, 32, EPI_BIAS_F32><<<dim3(32, 8), 256, 0, stream>>>(
        hb, W1t, b1, nullptr, 0, nullptr, hf, 2048, 512, 512);
    k_srms_relu<<<2048, 256, 0, stream>>>(hf, hb);
    k_gemm<64, 64, 32, 32, EPI_BIAS_F32><<<dim3(32, 8), 256, 0, stream>>>(
        hb, W2t, b2, nullptr, 0, nullptr, hf, 2048, 512, 512);
    k_srms_relu<<<2048, 256, 0, stream>>>(hf, hb);
    k_gemm<64, 64, 32, 32, EPI_BIAS_F32><<<dim3(32, 8), 256, 0, stream>>>(
        hb, W3t, b3, nullptr, 0, nullptr, hf, 2048, 512, 512);
    k_srms_relu<<<2048, 256, 0, stream>>>(hf, hb);
    // a[k,c] = gamma^k * (hb @ Wz + bz)[k,c]
    k_gemm<64, 64, 32, 32, EPI_DECAY_BF16><<<dim3(32, 16), 256, 0, stream>>>(
        hb, Wzt, bz, nullptr, 0, nullptr, ab, 2048, 1024, 512);

    // causal depthwise long conv + gate by u  (channel-pair packed f32 math)
    k_conv<<<dim3(32, 128), 64, 0, stream>>>(uvb, ab, ud1);

    // y = ud1 @ Wo + bo + x
    k_gemm<128, 128, 64, 64, EPI_BIAS_ADD_F32><<<dim3(64, 4), 256, 0, stream>>>(
        ud1, Wot, bo, nullptr, 0, x, d_out, 8192, 512, 1024);
}

// Round 3
// 319.177 us; speedup vs baseline: 1.5972x; 1.5267x over previous
//
#include <hip/hip_runtime.h>
#include <hip/hip_bf16.h>
#include <math.h>

using bf16 = __hip_bfloat16;
typedef short bf16x8 __attribute__((ext_vector_type(8)));
typedef float f32x4 __attribute__((ext_vector_type(4)));

#define GAMMA_LOG2 (-0.0014434688536725045f)  // log2(0.999)

__device__ inline unsigned int packbf2(float a, float b)
{
    union { bf16 h; unsigned short s; } x, y;
    x.h = __float2bfloat16(a);
    y.h = __float2bfloat16(b);
    return (unsigned int)x.s | ((unsigned int)y.s << 16);
}

// ---------- transpose + cast: fp32 (R x C) -> bf16 (C x R); R,C multiples of 32 ----------
__global__ void k_transpose_cast(const float* __restrict__ in, bf16* __restrict__ out, int R, int C)
{
    __shared__ float tile[32][33];
    int c0 = blockIdx.x * 32, r0 = blockIdx.y * 32;
    int tx = threadIdx.x & 31, ty = threadIdx.x >> 5;  // 256 threads: ty in 0..7
#pragma unroll
    for (int i = 0; i < 4; ++i) {
        int r = r0 + ty + 8 * i;
        tile[ty + 8 * i][tx] = in[(size_t)r * C + c0 + tx];
    }
    __syncthreads();
#pragma unroll
    for (int i = 0; i < 4; ++i) {
        int cc = c0 + ty + 8 * i, rr = r0 + tx;
        out[(size_t)cc * R + rr] = __float2bfloat16(tile[tx][ty + 8 * i]);
    }
}

// ---------- bf16 transpose: in (R x C slice at col0, row stride in_stride) -> out (C x R); batched via z ----------
__global__ void k_transpose_bf16(const bf16* __restrict__ in, bf16* __restrict__ out,
                                 int R, int C, int in_stride, int in_col0,
                                 size_t in_bstride, size_t out_bstride)
{
    __shared__ unsigned short tile[32][33];
    in += (size_t)blockIdx.z * in_bstride;
    out += (size_t)blockIdx.z * out_bstride;
    int c0 = blockIdx.x * 32, r0 = blockIdx.y * 32;
    int tx = threadIdx.x & 31, ty = threadIdx.x >> 5;
#pragma unroll
    for (int i = 0; i < 4; ++i) {
        int r = r0 + ty + 8 * i;
        tile[ty + 8 * i][tx] = *(const unsigned short*)(in + (size_t)r * in_stride + in_col0 + c0 + tx);
    }
    __syncthreads();
#pragma unroll
    for (int i = 0; i < 4; ++i) {
        int cc = c0 + ty + 8 * i, rr = r0 + tx;
        *(unsigned short*)(out + (size_t)cc * R + rr) = tile[tx][ty + 8 * i];
    }
}

// ---------- gate + transpose: ud1t[b](1024 x 2048) -> ud1[b](2048 x 1024), gated by u from uv (t,c) ----------
__global__ void k_gate_transpose(const bf16* __restrict__ ud1t, const bf16* __restrict__ uv,
                                 bf16* __restrict__ out)
{
    __shared__ float tile[32][33];
    const int b = blockIdx.z;
    int c0 = blockIdx.x * 32, t0 = blockIdx.y * 32;
    int tx = threadIdx.x & 31, ty = threadIdx.x >> 5;
#pragma unroll
    for (int i = 0; i < 4; ++i) {
        int cc = c0 + ty + 8 * i;
        tile[ty + 8 * i][tx] = __bfloat162float(ud1t[((size_t)b * 1024 + cc) * 2048 + t0 + tx]);
    }
    __syncthreads();
#pragma unroll
    for (int i = 0; i < 4; ++i) {
        int t = t0 + ty + 8 * i, c = c0 + tx;
        float u = __bfloat162float(uv[((size_t)b * 2048 + t) * 2048 + c]);
        out[((size_t)b * 2048 + t) * 1024 + c] = __float2bfloat16(tile[tx][ty + 8 * i] * u);
    }
}

// ---------- block reduction over 512 elems held 2-per-thread by 256 threads ----------
__device__ inline float block_sum_512(float v)
{
#pragma unroll
    for (int m = 32; m >= 1; m >>= 1) v += __shfl_xor(v, m, 64);
    __shared__ float ws[4];
    if ((threadIdx.x & 63) == 0) ws[threadIdx.x >> 6] = v;
    __syncthreads();
    return ws[0] + ws[1] + ws[2] + ws[3];
}

// ---------- x -> srms(x) as bf16 (rows of 512) ----------
__global__ void k_rms_x(const float* __restrict__ x, bf16* __restrict__ xn)
{
    int row = blockIdx.x, t = threadIdx.x;
    const float* xr = x + (size_t)row * 512;
    float a = xr[t], b = xr[t + 256];
    float tot = block_sum_512(a * a + b * b);
    float s = 1.f / (sqrtf(tot * (1.f / 512.f)) + 1e-8f);
    bf16* o = xn + (size_t)row * 512;
    o[t] = __float2bfloat16(a * s);
    o[t + 256] = __float2bfloat16(b * s);
}

// ---------- hcf0 = n*Wp + bp ; out = relu(srms(hcf0)) bf16 ----------
__global__ void k_mlp0(const float* __restrict__ Wp, const float* __restrict__ bp, bf16* __restrict__ out)
{
    int n = blockIdx.x, t = threadIdx.x;
    float fn = (float)n;
    float a = fn * Wp[t] + bp[t];
    float b = fn * Wp[t + 256] + bp[t + 256];
    float tot = block_sum_512(a * a + b * b);
    float s = 1.f / (sqrtf(tot * (1.f / 512.f)) + 1e-8f);
    bf16* o = out + (size_t)n * 512;
    o[t] = __float2bfloat16(fmaxf(a * s, 0.f));
    o[t + 256] = __float2bfloat16(fmaxf(b * s, 0.f));
}

// ---------- fp32 (rows x 512) -> relu(srms(.)) bf16 ----------
__global__ void k_srms_relu(const float* __restrict__ in, bf16* __restrict__ out)
{
    int row = blockIdx.x, t = threadIdx.x;
    const float* xr = in + (size_t)row * 512;
    float a = xr[t], b = xr[t + 256];
    float tot = block_sum_512(a * a + b * b);
    float s = 1.f / (sqrtf(tot * (1.f / 512.f)) + 1e-8f);
    bf16* o = out + (size_t)row * 512;
    o[t] = __float2bfloat16(fmaxf(a * s, 0.f));
    o[t + 256] = __float2bfloat16(fmaxf(b * s, 0.f));
}

// ---------- MFMA bf16 GEMM: A (MxK) row-major, Bt (NxK) row-major (pre-transposed weights) ----------
enum { EPI_SILU_BF16 = 0, EPI_BIAS_F32 = 1, EPI_DECAY_BF16 = 2, EPI_BIAS_ADD_F32 = 3 };

template <int BM, int BN, int WM, int WN, int EPI>
__global__ __launch_bounds__(256, 2) void k_gemm(
    const bf16* __restrict__ A, const bf16* __restrict__ Bt,
    const float* __restrict__ bias0, const float* __restrict__ bias1, int bsplit,
    const float* __restrict__ addsrc, void* __restrict__ outp,
    int M, int N, int K)
{
    constexpr int BK = 32, LDT = BK + 8;  // +8 bf16 pad -> 80B row stride, conflict-benign, 16B aligned
    constexpr int MI = WM / 16, NJ = WN / 16;
    constexpr int WCOLS = BN / WN;
    __shared__ unsigned short As[BM * LDT];
    __shared__ unsigned short Bs[BN * LDT];
    const int tid = threadIdx.x;
    const int lane = tid & 63, w = tid >> 6;
    const int wm = (w / WCOLS) * WM, wn = (w % WCOLS) * WN;
    const int lm = lane & 15, lq = lane >> 4;
    const long rowBase = (long)blockIdx.x * BM, colBase = (long)blockIdx.y * BN;

    f32x4 acc[MI][NJ];
    f32x4 zz = {0.f, 0.f, 0.f, 0.f};
#pragma unroll
    for (int i = 0; i < MI; ++i)
#pragma unroll
        for (int j = 0; j < NJ; ++j) acc[i][j] = zz;

    for (int k0 = 0; k0 < K; k0 += BK) {
#pragma unroll
        for (int i = 0; i < BM / 64; ++i) {
            int idx = (i * 256 + tid) * 8;
            int r = idx >> 5, kk = idx & 31;
            *(uint4*)(void*)(As + r * LDT + kk) =
                *(const uint4*)(const void*)(A + (rowBase + r) * K + k0 + kk);
        }
#pragma unroll
        for (int i = 0; i < BN / 64; ++i) {
            int idx = (i * 256 + tid) * 8;
            int r = idx >> 5, kk = idx & 31;
            *(uint4*)(void*)(Bs + r * LDT + kk) =
                *(const uint4*)(const void*)(Bt + (colBase + r) * K + k0 + kk);
        }
        __syncthreads();
        bf16x8 af[MI], bfr[NJ];
#pragma unroll
        for (int mi = 0; mi < MI; ++mi)
            af[mi] = *(const bf16x8*)(const void*)(As + (wm + mi * 16 + lm) * LDT + lq * 8);
#pragma unroll
        for (int nj = 0; nj < NJ; ++nj)
            bfr[nj] = *(const bf16x8*)(const void*)(Bs + (wn + nj * 16 + lm) * LDT + lq * 8);
#pragma unroll
        for (int mi = 0; mi < MI; ++mi)
#pragma unroll
            for (int nj = 0; nj < NJ; ++nj)
                acc[mi][nj] = __builtin_amdgcn_mfma_f32_16x16x32_bf16(af[mi], bfr[nj], acc[mi][nj], 0, 0, 0);
        __syncthreads();
    }

    // C/D layout (m89-verified): col = lane&15, row = (lane>>4)*4 + reg
#pragma unroll
    for (int mi = 0; mi < MI; ++mi)
#pragma unroll
        for (int nj = 0; nj < NJ; ++nj) {
            long col = colBase + wn + nj * 16 + lm;
#pragma unroll
            for (int r = 0; r < 4; ++r) {
                long row = rowBase + wm + mi * 16 + lq * 4 + r;
                float z = acc[mi][nj][r];
                size_t off = (size_t)row * N + col;
                if constexpr (EPI == EPI_SILU_BF16) {
                    float bb = (col < bsplit) ? bias0[col] : bias1[col - bsplit];
                    z += bb;
                    z = z / (1.f + __expf(-z));
                    ((bf16*)outp)[off] = __float2bfloat16(z);
                } else if constexpr (EPI == EPI_BIAS_F32) {
                    ((float*)outp)[off] = z + bias0[col];
                } else if constexpr (EPI == EPI_DECAY_BF16) {
                    z += bias0[col];
                    z *= exp2f((float)row * GAMMA_LOG2);  // gamma^row, row 0 -> 1
                    ((bf16*)outp)[off] = __float2bfloat16(z);
                } else {  // EPI_BIAS_ADD_F32: + bias + residual x
                    ((float*)outp)[off] = z + bias0[col] + addsrc[off];
                }
            }
        }
}

// ---------- Toeplitz-MFMA depthwise causal conv ----------
// Per wave: one (batch, channel); computes the full 2048-point causal conv via
// MFMA 16x16x32: D_jg[i, jc] = conv[16*(16*jg+jc) + i], reduction over diagonal
// pairs d = dd + h (h = k>>4): A[i,k=(h,p)] = a[16*(dd+h) + i - p] (Toeplitz, zero
// for negative index via LDS pad), B[k,jc] = v[16*(16*jg+jc - dd - h) + p]
// (zero-masked when the s-tile index is negative).
// vt: (b,c,t) bf16; at: (c,k) bf16; ud1t out: (b,c,t) bf16 (conv only, gating later).
__global__ __launch_bounds__(256, 4) void k_conv_mfma(
    const bf16* __restrict__ vt, const bf16* __restrict__ at, bf16* __restrict__ ud1t)
{
    __shared__ unsigned short vsh[4][2048];   // per-wave channel v row
    __shared__ unsigned short ash[4][2080];   // [0..15] = 0 pad (a[-16..-1]), [16..2063] = a[0..2047]

    const int tid = threadIdx.x, lane = tid & 63, w = tid >> 6;
    const int b = blockIdx.y;
    const int c = blockIdx.x * 4 + w;
    const bf16* vsrc = vt + ((size_t)b * 1024 + c) * 2048;
    const bf16* asrc = at + (size_t)c * 2048;

    // stage own channel (coalesced dwordx4)
#pragma unroll
    for (int q = 0; q < 4; ++q) {
        int e = q * 512 + lane * 8;
        *(uint4*)(void*)&vsh[w][e] = *(const uint4*)(const void*)(vsrc + e);
    }
    if (lane < 8) *(unsigned int*)(void*)&ash[w][lane * 2] = 0u;
#pragma unroll
    for (int q = 0; q < 4; ++q) {
        int e = q * 512 + lane * 8;
        *(uint4*)(void*)&ash[w][16 + e] = *(const uint4*)(const void*)(asrc + e);
    }
    __syncthreads();

    const int lm = lane & 15, lq = lane >> 4;
    const int h = lq >> 1, p0 = (lq & 1) * 8;
    const unsigned short* aw = &ash[w][0];
    const unsigned short* vw = &vsh[w][0];

    f32x4 acc[8];
    f32x4 zz = {0.f, 0.f, 0.f, 0.f};
#pragma unroll
    for (int i = 0; i < 8; ++i) acc[i] = zz;

    const int abase = 16 + 16 * h + lm - p0;  // + 16*dd - jj
    const bf16x8 zfrag = (bf16x8)(short)0;

    for (int dt = 0; dt < 8; ++dt) {
#pragma unroll
        for (int d2 = 0; d2 < 16; d2 += 2) {
            const int dd = dt * 16 + d2;
            const int ai = abase + 16 * dd;
            bf16x8 afrag;
#pragma unroll
            for (int jj = 0; jj < 8; ++jj) afrag[jj] = (short)aw[ai - jj];
            const int tb = lm - dd - h;  // tile = jg*16 + tb
            for (int jg = dt; jg < 8; ++jg) {
                int tile = jg * 16 + tb;
                int toff = (tile > 0 ? tile : 0) * 16 + p0;
                bf16x8 vf = *(const bf16x8*)(const void*)(vw + toff);
                if (tile < 0) vf = zfrag;
                acc[jg] = __builtin_amdgcn_mfma_f32_16x16x32_bf16(afrag, vf, acc[jg], 0, 0, 0);
            }
        }
    }

    // epilogue: D layout col=lm (jc), row=lq*4+r (i) -> t = jc*16 + i; reshuffle via LDS, write t-contiguous
    float* stg = (float*)(void*)&ash[w][0];  // 1 KB per jg, 16B-aligned; a no longer needed
    bf16* dst = ud1t + ((size_t)b * 1024 + c) * 2048;
#pragma unroll
    for (int jg = 0; jg < 8; ++jg) {
        *(f32x4*)(void*)&stg[lm * 16 + lq * 4] = acc[jg];
        f32x4 vv = *(const f32x4*)(const void*)&stg[lane * 4];  // same-wave DS pipe is in-order
        uint2 o;
        o.x = packbf2(vv.x, vv.y);
        o.y = packbf2(vv.z, vv.w);
        *(uint2*)(void*)(dst + jg * 256 + lane * 4) = o;
    }
}

extern "C" void kernel_launch(void* const* d_in, const int* in_sizes, int n_in,
                              void* d_out, int out_size, void* d_ws, size_t ws_size,
                              hipStream_t stream)
{
    const float* x  = (const float*)d_in[0];
    const float* Wu = (const float*)d_in[1];
    const float* bu = (const float*)d_in[2];
    const float* Wv = (const float*)d_in[3];
    const float* bv = (const float*)d_in[4];
    const float* Wo = (const float*)d_in[5];
    const float* bo = (const float*)d_in[6];
    const float* Wp = (const float*)d_in[7];
    const float* bp = (const float*)d_in[8];
    const float* W1 = (const float*)d_in[9];
    const float* b1 = (const float*)d_in[10];
    const float* W2 = (const float*)d_in[11];
    const float* b2 = (const float*)d_in[12];
    const float* W3 = (const float*)d_in[13];
    const float* b3 = (const float*)d_in[14];
    const float* Wz = (const float*)d_in[15];
    const float* bz = (const float*)d_in[16];

    char* p = (char*)d_ws;
    auto carve = [&](size_t bytes) { void* q = (void*)p; p += (bytes + 255) & ~(size_t)255; return q; };
    bf16*  xn   = (bf16*)carve((size_t)8192 * 512 * 2);
    bf16*  Wuvt = (bf16*)carve((size_t)2048 * 512 * 2);   // [Wu^T ; Wv^T], (2048 x 512)
    bf16*  Wot  = (bf16*)carve((size_t)512 * 1024 * 2);   // Wo^T (512 x 1024)
    bf16*  W1t  = (bf16*)carve((size_t)512 * 512 * 2);
    bf16*  W2t  = (bf16*)carve((size_t)512 * 512 * 2);
    bf16*  W3t  = (bf16*)carve((size_t)512 * 512 * 2);
    bf16*  Wzt  = (bf16*)carve((size_t)1024 * 512 * 2);   // Wz^T (1024 x 512)
    bf16*  uvb  = (bf16*)carve((size_t)8192 * 2048 * 2);  // [u | v] silu outputs (t, c)
    bf16*  ud1  = (bf16*)carve((size_t)8192 * 1024 * 2);  // u * conv, (t, c)
    bf16*  hb   = (bf16*)carve((size_t)2048 * 512 * 2);   // relu(srms(.)) bf16
    float* hf   = (float*)carve((size_t)2048 * 512 * 4);  // raw MLP GEMM out
    bf16*  ab   = (bf16*)carve((size_t)2048 * 1024 * 2);  // decayed filter a[k,c]
    bf16*  vtb  = (bf16*)carve((size_t)4 * 1024 * 2048 * 2);  // v transposed (b,c,t)
    bf16*  atb  = (bf16*)carve((size_t)1024 * 2048 * 2);      // a transposed (c,k)
    bf16*  ud1t = (bf16*)carve((size_t)4 * 1024 * 2048 * 2);  // conv result (b,c,t)

    // weight prep (transpose+cast so GEMM B-operand is k-contiguous)
    k_transpose_cast<<<dim3(32, 16), 256, 0, stream>>>(Wu, Wuvt, 512, 1024);
    k_transpose_cast<<<dim3(32, 16), 256, 0, stream>>>(Wv, Wuvt + (size_t)1024 * 512, 512, 1024);
    k_transpose_cast<<<dim3(16, 32), 256, 0, stream>>>(Wo, Wot, 1024, 512);
    k_transpose_cast<<<dim3(16, 16), 256, 0, stream>>>(W1, W1t, 512, 512);
    k_transpose_cast<<<dim3(16, 16), 256, 0, stream>>>(W2, W2t, 512, 512);
    k_transpose_cast<<<dim3(16, 16), 256, 0, stream>>>(W3, W3t, 512, 512);
    k_transpose_cast<<<dim3(32, 16), 256, 0, stream>>>(Wz, Wzt, 512, 1024);

    k_rms_x<<<8192, 256, 0, stream>>>(x, xn);

    // u|v = silu(xn @ [Wu|Wv] + [bu|bv])
    k_gemm<128, 128, 64, 64, EPI_SILU_BF16><<<dim3(64, 16), 256, 0, stream>>>(
        xn, Wuvt, bu, bv, 1024, nullptr, uvb, 8192, 2048, 512);

    // v -> (b, c, t)
    k_transpose_bf16<<<dim3(32, 64, 4), 256, 0, stream>>>(
        uvb, vtb, 2048, 1024, 2048, 1024, (size_t)2048 * 2048, (size_t)1024 * 2048);

    // positional filter MLP
    k_mlp0<<<2048, 256, 0, stream>>>(Wp, bp, hb);
    k_gemm<64, 64, 32, 32, EPI_BIAS_F32><<<dim3(32, 8), 256, 0, stream>>>(
        hb, W1t, b1, nullptr, 0, nullptr, hf, 2048, 512, 512);
    k_srms_relu<<<2048, 256, 0, stream>>>(hf, hb);
    k_gemm<64, 64, 32, 32, EPI_BIAS_F32><<<dim3(32, 8), 256, 0, stream>>>(
        hb, W2t, b2, nullptr, 0, nullptr, hf, 2048, 512, 512);
    k_srms_relu<<<2048, 256, 0, stream>>>(hf, hb);
    k_gemm<64, 64, 32, 32, EPI_BIAS_F32><<<dim3(32, 8), 256, 0, stream>>>(
        hb, W3t, b3, nullptr, 0, nullptr, hf, 2048, 512, 512);
    k_srms_relu<<<2048, 256, 0, stream>>>(hf, hb);
    // a[k,c] = gamma^k * (hb @ Wz + bz)[k,c]
    k_gemm<64, 64, 32, 32, EPI_DECAY_BF16><<<dim3(32, 16), 256, 0, stream>>>(
        hb, Wzt, bz, nullptr, 0, nullptr, ab, 2048, 1024, 512);

    // a -> (c, k)
    k_transpose_bf16<<<dim3(32, 64, 1), 256, 0, stream>>>(
        ab, atb, 2048, 1024, 1024, 0, 0, 0);

    // causal depthwise conv via Toeplitz-MFMA (one wave per (b, c))
    k_conv_mfma<<<dim3(256, 4), 256, 0, stream>>>(vtb, atb, ud1t);

    // gate by u and transpose back to (t, c)
    k_gate_transpose<<<dim3(32, 64, 4), 256, 0, stream>>>(ud1t, uvb, ud1);

    // y = ud1 @ Wo + bo + x
    k_gemm<128, 128, 64, 64, EPI_BIAS_ADD_F32><<<dim3(64, 4), 256, 0, stream>>>(
        ud1, Wot, bo, nullptr, 0, x, d_out, 8192, 512, 1024);
}